// Round 13
// baseline (1019.263 us; speedup 1.0000x reference)
//
#include <hip/hip_runtime.h>
#include <math.h>

// GPT-2 block forward. B=64, T=256, C=1024, H=16, D=64, M=16384.
// Round 13 = rounds 9-12 resubmitted (broker timeouts / one container
// failure; never executed). If next result is another CONTAINER failure,
// revert staging to round-8 reg-staged form to isolate kernel-vs-infra.
// gemm_mfma staging = async global_load_lds (16 B/lane, m97 pattern).
// LDS dest linear (tid*16 B); k-group XOR swizzle pre-applied in the
// per-lane GLOBAL source address; LDS read side unchanged.
// Attention/LN/wconv identical to round 8 (907 us, fc GEMM 243 us).

#define C_DIM   1024
#define NHEAD   16
#define HDIM    64
#define TSEQ    256
#define BATCH   64

typedef __attribute__((ext_vector_type(4))) float fx4;
typedef __attribute__((ext_vector_type(8))) short sx8;

typedef const __attribute__((address_space(1))) void* gvp;
typedef __attribute__((address_space(3))) void* lvp;

__device__ __forceinline__ void gload16(const ushort* g, ushort* l) {
    __builtin_amdgcn_global_load_lds((gvp)g, (lvp)l, 16, 0, 0);
}

__device__ __forceinline__ ushort f2bf(float f) {
    uint x = __float_as_uint(f);
    x += 0x7fffu + ((x >> 16) & 1u);          // round-to-nearest-even
    return (ushort)(x >> 16);
}
__device__ __forceinline__ float bf2f(ushort u) {
    return __uint_as_float(((uint)u) << 16);
}

// ---------------------------------------------------------------------------
// Weight convert+transpose: W[K][N] fp32 -> Wt[N][K] bf16. 64x64 tiles.
// ---------------------------------------------------------------------------
__global__ __launch_bounds__(256)
void wconv(const float* __restrict__ W, ushort* __restrict__ Wt, int K, int N)
{
    __shared__ float T[64][65];
    const int kt = blockIdx.x << 6, nt = blockIdx.y << 6;
    const int ln = threadIdx.x & 63, g4 = threadIdx.x >> 6;
    #pragma unroll
    for (int i = 0; i < 16; ++i) {
        const int r = i * 4 + g4;
        T[r][ln] = W[(size_t)(kt + r) * N + nt + ln];
    }
    __syncthreads();
    #pragma unroll
    for (int i = 0; i < 16; ++i) {
        const int r = i * 4 + g4;
        Wt[(size_t)(nt + r) * K + kt + ln] = f2bf(T[ln][r]);
    }
}

// ---------------------------------------------------------------------------
// LayerNorm fp32 in -> bf16 out. One block per 1024-float row.
// ---------------------------------------------------------------------------
__global__ __launch_bounds__(256)
void ln_bf16(const float* __restrict__ x, const float* __restrict__ w,
             const float* __restrict__ b, ushort* __restrict__ out)
{
    const int row = blockIdx.x;
    const int tid = threadIdx.x;
    const float4 v = reinterpret_cast<const float4*>(x + (size_t)row * C_DIM)[tid];

    float s  = v.x + v.y + v.z + v.w;
    float ss = v.x * v.x + v.y * v.y + v.z * v.z + v.w * v.w;
    #pragma unroll
    for (int off = 32; off > 0; off >>= 1) {
        s  += __shfl_down(s, off);
        ss += __shfl_down(ss, off);
    }
    __shared__ float rs[4], rss[4];
    const int wid = tid >> 6, lane = tid & 63;
    if (lane == 0) { rs[wid] = s; rss[wid] = ss; }
    __syncthreads();
    if (tid == 0) {
        const float S  = rs[0] + rs[1] + rs[2] + rs[3];
        const float SS = rss[0] + rss[1] + rss[2] + rss[3];
        const float mu  = S * (1.0f / C_DIM);
        const float var = SS * (1.0f / C_DIM) - mu * mu;
        rs[0]  = mu;
        rss[0] = rsqrtf(var + 1e-5f);
    }
    __syncthreads();
    const float mu = rs[0], rstd = rss[0];

    const float4 wv = reinterpret_cast<const float4*>(w)[tid];
    const float4 bv = reinterpret_cast<const float4*>(b)[tid];
    ushort4 o;
    o.x = f2bf((v.x - mu) * rstd * wv.x + bv.x);
    o.y = f2bf((v.y - mu) * rstd * wv.y + bv.y);
    o.z = f2bf((v.z - mu) * rstd * wv.z + bv.z);
    o.w = f2bf((v.w - mu) * rstd * wv.w + bv.w);
    reinterpret_cast<ushort4*>(out + (size_t)row * C_DIM)[tid] = o;
}

// ---------------------------------------------------------------------------
// bf16 MFMA GEMM (NT): C[M,N] = A[M,K] * Wt[N,K]^T + bias (+res) (+gelu)
// 128x128 tile, BK=32, 256 threads (4 waves, 2x2), 64x64 per wave.
// Staging: global_load_lds 16B/lane. LDS dest linear (byte off = tid*16);
// source k-group = (tid&3) ^ ((srow>>1)&3) pre-swizzled in the global addr.
// EPI: 0 = bf16 out + bias; 1 = fp32 out + bias + res; 2 = bf16 out + bias + gelu
// ---------------------------------------------------------------------------
template<int EPI>
__global__ __launch_bounds__(256)
void gemm_mfma(const ushort* __restrict__ A, const ushort* __restrict__ Wt,
               const float* __restrict__ bias, const float* __restrict__ res,
               void* __restrict__ outv, int M, int N, int K)
{
    __shared__ ushort As[128 * 32];
    __shared__ ushort Bs[128 * 32];

    const int tid  = threadIdx.x;
    const int lane = tid & 63;
    const int wid  = tid >> 6;
    const int wr   = (wid >> 1) << 6;
    const int wc   = (wid & 1) << 6;
    const int bm = blockIdx.x << 7;
    const int bn = blockIdx.y << 7;

    // per-lane global sources (k-group swizzled); per-wave uniform LDS bases
    const int srow = tid >> 2;
    const int spos = tid & 3;
    const int skg  = spos ^ ((srow >> 1) & 3);
    const ushort* pa0 = A  + (size_t)(bm + srow)      * K + skg * 8;
    const ushort* pa1 = A  + (size_t)(bm + srow + 64) * K + skg * 8;
    const ushort* pb0 = Wt + (size_t)(bn + srow)      * K + skg * 8;
    const ushort* pb1 = Wt + (size_t)(bn + srow + 64) * K + skg * 8;
    ushort* lA0 = As + wid * 512;          // wave covers bytes [wid*1024, +1024)
    ushort* lA1 = As + wid * 512 + 2048;   // rows +64: byte offset +4096
    ushort* lB0 = Bs + wid * 512;
    ushort* lB1 = Bs + wid * 512 + 2048;

    // fragment read offsets (unchanged): lane gives row (lane&15), kgrp (lane>>4)
    const int frow = lane & 15;
    const int fpos = ((lane >> 4) ^ ((frow >> 1) & 3)) * 8;
    int aoff[4], boff[4];
    #pragma unroll
    for (int i = 0; i < 4; ++i) {
        aoff[i] = (wr + i * 16 + frow) * 32 + fpos;
        boff[i] = (wc + i * 16 + frow) * 32 + fpos;
    }

    fx4 acc[4][4] = {};
    const int nk = K >> 5;

    for (int t = 0; t < nk; ++t) {
        const int ko = t << 5;
        __syncthreads();                   // previous tile's compute done
        gload16(pa0 + ko, lA0);
        gload16(pa1 + ko, lA1);
        gload16(pb0 + ko, lB0);
        gload16(pb1 + ko, lB1);
        __syncthreads();                   // vmcnt(0) drained before barrier

        sx8 af[4], bf[4];
        #pragma unroll
        for (int i = 0; i < 4; ++i) af[i] = *(const sx8*)&As[aoff[i]];
        #pragma unroll
        for (int i = 0; i < 4; ++i) bf[i] = *(const sx8*)&Bs[boff[i]];
        #pragma unroll
        for (int i = 0; i < 4; ++i)
            #pragma unroll
            for (int j = 0; j < 4; ++j)
                acc[i][j] = __builtin_amdgcn_mfma_f32_16x16x32_bf16(
                    af[i], bf[j], acc[i][j], 0, 0, 0);
    }

    // epilogue: D row = (lane>>4)*4 + reg, col = lane&15  [HW-verified m89/m91]
    const int r0 = bm + wr + (lane >> 4) * 4;
    const int c0 = bn + wc + (lane & 15);
    #pragma unroll
    for (int i = 0; i < 4; ++i) {
        #pragma unroll
        for (int r = 0; r < 4; ++r) {
            const int row = r0 + i * 16 + r;
            #pragma unroll
            for (int j = 0; j < 4; ++j) {
                const int col = c0 + j * 16;
                float v = acc[i][j][r] + bias[col];
                if (EPI == 1) {
                    v += res[(size_t)row * N + col];
                    ((float*)outv)[(size_t)row * N + col] = v;
                } else if (EPI == 2) {
                    v = 0.5f * v * (1.0f + erff(v * 0.70710678118654752f));
                    ((ushort*)outv)[(size_t)row * N + col] = f2bf(v);
                } else {
                    ((ushort*)outv)[(size_t)row * N + col] = f2bf(v);
                }
            }
        }
    }
}

// ---------------------------------------------------------------------------
// MFMA flash attention (unchanged from round 8; dropped out of top-5).
// ---------------------------------------------------------------------------
__global__ __launch_bounds__(256, 1)
void attn_mfma(const ushort* __restrict__ qkv, ushort* __restrict__ y)
{
    __shared__ ushort Ks[256 * 72];
    __shared__ ushort Vt[64 * 264];
    __shared__ ushort Pl[4][64 * 72];

    const int bl = blockIdx.x >> 4;
    const int h  = blockIdx.x & 15;
    const size_t base = (size_t)bl * TSEQ * 3072 + (size_t)h * HDIM;

    const int tid  = threadIdx.x;
    const int lane = tid & 63;
    const int w    = tid >> 6;
    const int c15  = lane & 15;
    const int grp  = lane >> 4;

    {
        const int kv = tid;
        const ushort* kp = qkv + base + (size_t)kv * 3072 + 1024;
        const ushort* vp = qkv + base + (size_t)kv * 3072 + 2048;
        #pragma unroll
        for (int j = 0; j < 8; ++j) {
            sx8 k8 = *(const sx8*)(kp + j * 8);
            *(sx8*)&Ks[kv * 72 + j * 8] = k8;
            sx8 v8 = *(const sx8*)(vp + j * 8);
            #pragma unroll
            for (int e = 0; e < 8; ++e)
                Vt[(j * 8 + e) * 264 + kv] = (ushort)v8[e];
        }
    }

    sx8 aq[4][2];
    #pragma unroll
    for (int m = 0; m < 4; ++m)
        #pragma unroll
        for (int kc = 0; kc < 2; ++kc) {
            const int qr = w * 64 + m * 16 + c15;
            aq[m][kc] = *(const sx8*)(qkv + base + (size_t)qr * 3072 + kc * 32 + grp * 8);
        }

    __syncthreads();

    fx4 oacc[4][4] = {};
    float m_s[4][4], l_s[4][4];
    #pragma unroll
    for (int m = 0; m < 4; ++m)
        #pragma unroll
        for (int r = 0; r < 4; ++r) { m_s[m][r] = -INFINITY; l_s[m][r] = 0.0f; }

    for (int t = 0; t <= w; ++t) {
        const int kt = t * 64;
        const bool diag = (t == w);

        fx4 s[4][4] = {};
        #pragma unroll
        for (int kc = 0; kc < 2; ++kc)
            #pragma unroll
            for (int n = 0; n < 4; ++n) {
                sx8 bk = *(const sx8*)&Ks[(kt + n * 16 + c15) * 72 + kc * 32 + grp * 8];
                #pragma unroll
                for (int m = 0; m < 4; ++m)
                    s[m][n] = __builtin_amdgcn_mfma_f32_16x16x32_bf16(
                        aq[m][kc], bk, s[m][n], 0, 0, 0);
            }

        #pragma unroll
        for (int m = 0; m < 4; ++m)
            #pragma unroll
            for (int n = 0; n < 4; ++n)
                #pragma unroll
                for (int r = 0; r < 4; ++r) {
                    float v = s[m][n][r] * 0.125f;
                    if (diag && (n * 16 + c15) > (m * 16 + grp * 4 + r)) v = -1e30f;
                    s[m][n][r] = v;
                }

        #pragma unroll
        for (int m = 0; m < 4; ++m)
            #pragma unroll
            for (int r = 0; r < 4; ++r) {
                float mx = fmaxf(fmaxf(s[m][0][r], s[m][1][r]),
                                 fmaxf(s[m][2][r], s[m][3][r]));
                #pragma unroll
                for (int off = 1; off < 16; off <<= 1)
                    mx = fmaxf(mx, __shfl_xor(mx, off));
                const float mnew = fmaxf(m_s[m][r], mx);
                const float cold = __expf(m_s[m][r] - mnew);
                m_s[m][r] = mnew;
                float rsum = 0.0f;
                #pragma unroll
                for (int n = 0; n < 4; ++n) {
                    const float p = __expf(s[m][n][r] - mnew);
                    s[m][n][r] = p;
                    rsum += p;
                }
                #pragma unroll
                for (int off = 1; off < 16; off <<= 1)
                    rsum += __shfl_xor(rsum, off);
                l_s[m][r] = l_s[m][r] * cold + rsum;
                #pragma unroll
                for (int dn = 0; dn < 4; ++dn)
                    oacc[m][dn][r] *= cold;
            }

        #pragma unroll
        for (int m = 0; m < 4; ++m)
            #pragma unroll
            for (int n = 0; n < 4; ++n)
                #pragma unroll
                for (int r = 0; r < 4; ++r)
                    Pl[w][(m * 16 + grp * 4 + r) * 72 + n * 16 + c15] =
                        f2bf(s[m][n][r]);

        #pragma unroll
        for (int kc = 0; kc < 2; ++kc) {
            sx8 ap[4];
            #pragma unroll
            for (int m = 0; m < 4; ++m)
                ap[m] = *(const sx8*)&Pl[w][(m * 16 + c15) * 72 + kc * 32 + grp * 8];
            #pragma unroll
            for (int dn = 0; dn < 4; ++dn) {
                sx8 bv = *(const sx8*)&Vt[(dn * 16 + c15) * 264 + kt + kc * 32 + grp * 8];
                #pragma unroll
                for (int m = 0; m < 4; ++m)
                    oacc[m][dn] = __builtin_amdgcn_mfma_f32_16x16x32_bf16(
                        ap[m], bv, oacc[m][dn], 0, 0, 0);
            }
        }
    }

    #pragma unroll
    for (int m = 0; m < 4; ++m)
        #pragma unroll
        for (int r = 0; r < 4; ++r) {
            const float inv = 1.0f / l_s[m][r];
            const int row = bl * TSEQ + w * 64 + m * 16 + grp * 4 + r;
            ushort* yp = y + (size_t)row * C_DIM + h * HDIM;
            #pragma unroll
            for (int dn = 0; dn < 4; ++dn)
                yp[dn * 16 + c15] = f2bf(oacc[m][dn][r] * inv);
        }
}

// ---------------------------------------------------------------------------
extern "C" void kernel_launch(void* const* d_in, const int* in_sizes, int n_in,
                              void* d_out, int out_size, void* d_ws, size_t ws_size,
                              hipStream_t stream)
{
    const float* x      = (const float*)d_in[0];
    const float* ln1_w  = (const float*)d_in[1];
    const float* ln1_b  = (const float*)d_in[2];
    const float* w_attn = (const float*)d_in[3];
    const float* b_attn = (const float*)d_in[4];
    const float* w_proj = (const float*)d_in[5];
    const float* b_proj = (const float*)d_in[6];
    const float* ln2_w  = (const float*)d_in[7];
    const float* ln2_b  = (const float*)d_in[8];
    const float* w_fc   = (const float*)d_in[9];
    const float* b_fc   = (const float*)d_in[10];
    const float* w_out  = (const float*)d_in[11];
    const float* b_out  = (const float*)d_in[12];
    float* out = (float*)d_out;

    ushort* wbf     = (ushort*)d_ws;
    ushort* wt_attn = wbf;                 // 1024*3072
    ushort* wt_proj = wbf + 3145728;       // 1024*1024
    ushort* wt_fc   = wbf + 4194304;       // 1024*4096
    ushort* wt_out  = wbf + 8388608;       // 4096*1024
    const size_t wbytes = 12582912ull * 2;

    int nchunk = 64;
    for (int cand = 1; cand <= 64; cand *= 2) {
        const size_t rows = (size_t)(BATCH / cand) * TSEQ;
        if (wbytes + rows * 10240ull <= ws_size) { nchunk = cand; break; }
    }
    const int bchunk = BATCH / nchunk;
    const int rows   = bchunk * TSEQ;

    ushort* hbuf = wbf + 12582912;
    ushort* qkvb = hbuf + (size_t)rows * 1024;
    ushort* ybuf = qkvb + (size_t)rows * 3072;
    ushort* act  = qkvb;                   // rows*4096 spans qkvb+ybuf

    wconv<<<dim3(16, 48), 256, 0, stream>>>(w_attn, wt_attn, 1024, 3072);
    wconv<<<dim3(16, 16), 256, 0, stream>>>(w_proj, wt_proj, 1024, 1024);
    wconv<<<dim3(16, 64), 256, 0, stream>>>(w_fc,   wt_fc,   1024, 4096);
    wconv<<<dim3(64, 16), 256, 0, stream>>>(w_out,  wt_out,  4096, 1024);

    for (int c = 0; c < nchunk; ++c) {
        const size_t r0 = (size_t)c * rows;
        const float* xc = x   + r0 * C_DIM;
        float*       oc = out + r0 * C_DIM;
        ln_bf16<<<rows, 256, 0, stream>>>(xc, ln1_w, ln1_b, hbuf);
        gemm_mfma<0><<<dim3(rows / 128, 3072 / 128), 256, 0, stream>>>(
            hbuf, wt_attn, b_attn, nullptr, qkvb, rows, 3072, 1024);
        attn_mfma<<<bchunk * NHEAD, 256, 0, stream>>>(qkvb, ybuf);
        gemm_mfma<1><<<dim3(rows / 128, 1024 / 128), 256, 0, stream>>>(
            ybuf, wt_proj, b_proj, xc, oc, rows, 1024, 1024);
    }

    for (int c = 0; c < nchunk; ++c) {
        const size_t r0 = (size_t)c * rows;
        float* oc = out + r0 * C_DIM;
        ln_bf16<<<rows, 256, 0, stream>>>(oc, ln2_w, ln2_b, hbuf);
        gemm_mfma<2><<<dim3(rows / 128, 4096 / 128), 256, 0, stream>>>(
            hbuf, wt_fc, b_fc, nullptr, act, rows, 4096, 1024);
        gemm_mfma<1><<<dim3(rows / 128, 1024 / 128), 256, 0, stream>>>(
            act, wt_out, b_out, oc, oc, rows, 1024, 4096);
    }
}

// Round 14
// 976.023 us; speedup vs baseline: 1.0443x; 1.0443x over previous
//
#include <hip/hip_runtime.h>
#include <math.h>

// GPT-2 block forward. B=64, T=256, C=1024, H=16, D=64, M=16384.
// Round 14: fix round-13 regression (1019us; 2-barrier gload_lds exposed
// full load latency every K-step). gemm_mfma now double-buffers LDS and
// issues tile t+1's global_load_lds BEFORE computing tile t (T3 minimum
// 2-phase recipe): the end-of-iteration __syncthreads' vmcnt(0) drain
// lands after the MFMA block, hiding load latency under compute.
// One barrier per K-step. Everything else identical to round 13.

#define C_DIM   1024
#define NHEAD   16
#define HDIM    64
#define TSEQ    256
#define BATCH   64

typedef __attribute__((ext_vector_type(4))) float fx4;
typedef __attribute__((ext_vector_type(8))) short sx8;

typedef const __attribute__((address_space(1))) void* gvp;
typedef __attribute__((address_space(3))) void* lvp;

__device__ __forceinline__ void gload16(const ushort* g, ushort* l) {
    __builtin_amdgcn_global_load_lds((gvp)g, (lvp)l, 16, 0, 0);
}

__device__ __forceinline__ ushort f2bf(float f) {
    uint x = __float_as_uint(f);
    x += 0x7fffu + ((x >> 16) & 1u);          // round-to-nearest-even
    return (ushort)(x >> 16);
}
__device__ __forceinline__ float bf2f(ushort u) {
    return __uint_as_float(((uint)u) << 16);
}

// ---------------------------------------------------------------------------
// Weight convert+transpose: W[K][N] fp32 -> Wt[N][K] bf16. 64x64 tiles.
// ---------------------------------------------------------------------------
__global__ __launch_bounds__(256)
void wconv(const float* __restrict__ W, ushort* __restrict__ Wt, int K, int N)
{
    __shared__ float T[64][65];
    const int kt = blockIdx.x << 6, nt = blockIdx.y << 6;
    const int ln = threadIdx.x & 63, g4 = threadIdx.x >> 6;
    #pragma unroll
    for (int i = 0; i < 16; ++i) {
        const int r = i * 4 + g4;
        T[r][ln] = W[(size_t)(kt + r) * N + nt + ln];
    }
    __syncthreads();
    #pragma unroll
    for (int i = 0; i < 16; ++i) {
        const int r = i * 4 + g4;
        Wt[(size_t)(nt + r) * K + kt + ln] = f2bf(T[ln][r]);
    }
}

// ---------------------------------------------------------------------------
// LayerNorm fp32 in -> bf16 out. One block per 1024-float row.
// ---------------------------------------------------------------------------
__global__ __launch_bounds__(256)
void ln_bf16(const float* __restrict__ x, const float* __restrict__ w,
             const float* __restrict__ b, ushort* __restrict__ out)
{
    const int row = blockIdx.x;
    const int tid = threadIdx.x;
    const float4 v = reinterpret_cast<const float4*>(x + (size_t)row * C_DIM)[tid];

    float s  = v.x + v.y + v.z + v.w;
    float ss = v.x * v.x + v.y * v.y + v.z * v.z + v.w * v.w;
    #pragma unroll
    for (int off = 32; off > 0; off >>= 1) {
        s  += __shfl_down(s, off);
        ss += __shfl_down(ss, off);
    }
    __shared__ float rs[4], rss[4];
    const int wid = tid >> 6, lane = tid & 63;
    if (lane == 0) { rs[wid] = s; rss[wid] = ss; }
    __syncthreads();
    if (tid == 0) {
        const float S  = rs[0] + rs[1] + rs[2] + rs[3];
        const float SS = rss[0] + rss[1] + rss[2] + rss[3];
        const float mu  = S * (1.0f / C_DIM);
        const float var = SS * (1.0f / C_DIM) - mu * mu;
        rs[0]  = mu;
        rss[0] = rsqrtf(var + 1e-5f);
    }
    __syncthreads();
    const float mu = rs[0], rstd = rss[0];

    const float4 wv = reinterpret_cast<const float4*>(w)[tid];
    const float4 bv = reinterpret_cast<const float4*>(b)[tid];
    ushort4 o;
    o.x = f2bf((v.x - mu) * rstd * wv.x + bv.x);
    o.y = f2bf((v.y - mu) * rstd * wv.y + bv.y);
    o.z = f2bf((v.z - mu) * rstd * wv.z + bv.z);
    o.w = f2bf((v.w - mu) * rstd * wv.w + bv.w);
    reinterpret_cast<ushort4*>(out + (size_t)row * C_DIM)[tid] = o;
}

// ---------------------------------------------------------------------------
// bf16 MFMA GEMM (NT): C[M,N] = A[M,K] * Wt[N,K]^T + bias (+res) (+gelu)
// 128x128 tile, BK=32, 256 threads (4 waves, 2x2), 64x64 per wave.
// Double-buffered LDS; tile t+1's global_load_lds issued before tile t's
// compute; single __syncthreads per K-step (vmcnt drain after compute).
// EPI: 0 = bf16 out + bias; 1 = fp32 out + bias + res; 2 = bf16 out + bias + gelu
// ---------------------------------------------------------------------------
template<int EPI>
__global__ __launch_bounds__(256)
void gemm_mfma(const ushort* __restrict__ A, const ushort* __restrict__ Wt,
               const float* __restrict__ bias, const float* __restrict__ res,
               void* __restrict__ outv, int M, int N, int K)
{
    __shared__ ushort As[2][128 * 32];
    __shared__ ushort Bs[2][128 * 32];

    const int tid  = threadIdx.x;
    const int lane = tid & 63;
    const int wid  = tid >> 6;
    const int wr   = (wid >> 1) << 6;
    const int wc   = (wid & 1) << 6;
    const int bm = blockIdx.x << 7;
    const int bn = blockIdx.y << 7;

    // per-lane global sources (k-group swizzled); per-wave uniform LDS bases
    const int srow = tid >> 2;
    const int spos = tid & 3;
    const int skg  = spos ^ ((srow >> 1) & 3);
    const ushort* pa0 = A  + (size_t)(bm + srow)      * K + skg * 8;
    const ushort* pa1 = A  + (size_t)(bm + srow + 64) * K + skg * 8;
    const ushort* pb0 = Wt + (size_t)(bn + srow)      * K + skg * 8;
    const ushort* pb1 = Wt + (size_t)(bn + srow + 64) * K + skg * 8;
    const int wo = wid * 512;              // wave's linear slot: byte wid*1024

    // fragment read offsets: lane gives row (lane&15), kgrp (lane>>4)
    const int frow = lane & 15;
    const int fpos = ((lane >> 4) ^ ((frow >> 1) & 3)) * 8;
    int aoff[4], boff[4];
    #pragma unroll
    for (int i = 0; i < 4; ++i) {
        aoff[i] = (wr + i * 16 + frow) * 32 + fpos;
        boff[i] = (wc + i * 16 + frow) * 32 + fpos;
    }

    fx4 acc[4][4] = {};
    const int nk = K >> 5;

    // prologue: stage tile 0 into buffer 0
    gload16(pa0, &As[0][wo]);
    gload16(pa1, &As[0][wo + 2048]);
    gload16(pb0, &Bs[0][wo]);
    gload16(pb1, &Bs[0][wo + 2048]);
    __syncthreads();                       // vmcnt(0): buffer 0 ready

    for (int t = 0; t < nk; ++t) {
        const int cur = t & 1;
        if (t + 1 < nk) {                  // prefetch t+1 into other buffer
            const int nb = cur ^ 1;
            const int ko = (t + 1) << 5;
            gload16(pa0 + ko, &As[nb][wo]);
            gload16(pa1 + ko, &As[nb][wo + 2048]);
            gload16(pb0 + ko, &Bs[nb][wo]);
            gload16(pb1 + ko, &Bs[nb][wo + 2048]);
        }

        sx8 af[4], bf[4];
        #pragma unroll
        for (int i = 0; i < 4; ++i) af[i] = *(const sx8*)&As[cur][aoff[i]];
        #pragma unroll
        for (int i = 0; i < 4; ++i) bf[i] = *(const sx8*)&Bs[cur][boff[i]];
        #pragma unroll
        for (int i = 0; i < 4; ++i)
            #pragma unroll
            for (int j = 0; j < 4; ++j)
                acc[i][j] = __builtin_amdgcn_mfma_f32_16x16x32_bf16(
                    af[i], bf[j], acc[i][j], 0, 0, 0);

        // one barrier per K-step: drains vmcnt (t+1 loads done, after compute)
        // and lgkmcnt (all waves' reads of buf[cur] done before overwrite).
        __syncthreads();
    }

    // epilogue: D row = (lane>>4)*4 + reg, col = lane&15  [HW-verified m89/m91]
    const int r0 = bm + wr + (lane >> 4) * 4;
    const int c0 = bn + wc + (lane & 15);
    #pragma unroll
    for (int i = 0; i < 4; ++i) {
        #pragma unroll
        for (int r = 0; r < 4; ++r) {
            const int row = r0 + i * 16 + r;
            #pragma unroll
            for (int j = 0; j < 4; ++j) {
                const int col = c0 + j * 16;
                float v = acc[i][j][r] + bias[col];
                if (EPI == 1) {
                    v += res[(size_t)row * N + col];
                    ((float*)outv)[(size_t)row * N + col] = v;
                } else if (EPI == 2) {
                    v = 0.5f * v * (1.0f + erff(v * 0.70710678118654752f));
                    ((ushort*)outv)[(size_t)row * N + col] = f2bf(v);
                } else {
                    ((ushort*)outv)[(size_t)row * N + col] = f2bf(v);
                }
            }
        }
    }
}

// ---------------------------------------------------------------------------
// MFMA flash attention (unchanged from round 8).
// ---------------------------------------------------------------------------
__global__ __launch_bounds__(256, 1)
void attn_mfma(const ushort* __restrict__ qkv, ushort* __restrict__ y)
{
    __shared__ ushort Ks[256 * 72];
    __shared__ ushort Vt[64 * 264];
    __shared__ ushort Pl[4][64 * 72];

    const int bl = blockIdx.x >> 4;
    const int h  = blockIdx.x & 15;
    const size_t base = (size_t)bl * TSEQ * 3072 + (size_t)h * HDIM;

    const int tid  = threadIdx.x;
    const int lane = tid & 63;
    const int w    = tid >> 6;
    const int c15  = lane & 15;
    const int grp  = lane >> 4;

    {
        const int kv = tid;
        const ushort* kp = qkv + base + (size_t)kv * 3072 + 1024;
        const ushort* vp = qkv + base + (size_t)kv * 3072 + 2048;
        #pragma unroll
        for (int j = 0; j < 8; ++j) {
            sx8 k8 = *(const sx8*)(kp + j * 8);
            *(sx8*)&Ks[kv * 72 + j * 8] = k8;
            sx8 v8 = *(const sx8*)(vp + j * 8);
            #pragma unroll
            for (int e = 0; e < 8; ++e)
                Vt[(j * 8 + e) * 264 + kv] = (ushort)v8[e];
        }
    }

    sx8 aq[4][2];
    #pragma unroll
    for (int m = 0; m < 4; ++m)
        #pragma unroll
        for (int kc = 0; kc < 2; ++kc) {
            const int qr = w * 64 + m * 16 + c15;
            aq[m][kc] = *(const sx8*)(qkv + base + (size_t)qr * 3072 + kc * 32 + grp * 8);
        }

    __syncthreads();

    fx4 oacc[4][4] = {};
    float m_s[4][4], l_s[4][4];
    #pragma unroll
    for (int m = 0; m < 4; ++m)
        #pragma unroll
        for (int r = 0; r < 4; ++r) { m_s[m][r] = -INFINITY; l_s[m][r] = 0.0f; }

    for (int t = 0; t <= w; ++t) {
        const int kt = t * 64;
        const bool diag = (t == w);

        fx4 s[4][4] = {};
        #pragma unroll
        for (int kc = 0; kc < 2; ++kc)
            #pragma unroll
            for (int n = 0; n < 4; ++n) {
                sx8 bk = *(const sx8*)&Ks[(kt + n * 16 + c15) * 72 + kc * 32 + grp * 8];
                #pragma unroll
                for (int m = 0; m < 4; ++m)
                    s[m][n] = __builtin_amdgcn_mfma_f32_16x16x32_bf16(
                        aq[m][kc], bk, s[m][n], 0, 0, 0);
            }

        #pragma unroll
        for (int m = 0; m < 4; ++m)
            #pragma unroll
            for (int n = 0; n < 4; ++n)
                #pragma unroll
                for (int r = 0; r < 4; ++r) {
                    float v = s[m][n][r] * 0.125f;
                    if (diag && (n * 16 + c15) > (m * 16 + grp * 4 + r)) v = -1e30f;
                    s[m][n][r] = v;
                }

        #pragma unroll
        for (int m = 0; m < 4; ++m)
            #pragma unroll
            for (int r = 0; r < 4; ++r) {
                float mx = fmaxf(fmaxf(s[m][0][r], s[m][1][r]),
                                 fmaxf(s[m][2][r], s[m][3][r]));
                #pragma unroll
                for (int off = 1; off < 16; off <<= 1)
                    mx = fmaxf(mx, __shfl_xor(mx, off));
                const float mnew = fmaxf(m_s[m][r], mx);
                const float cold = __expf(m_s[m][r] - mnew);
                m_s[m][r] = mnew;
                float rsum = 0.0f;
                #pragma unroll
                for (int n = 0; n < 4; ++n) {
                    const float p = __expf(s[m][n][r] - mnew);
                    s[m][n][r] = p;
                    rsum += p;
                }
                #pragma unroll
                for (int off = 1; off < 16; off <<= 1)
                    rsum += __shfl_xor(rsum, off);
                l_s[m][r] = l_s[m][r] * cold + rsum;
                #pragma unroll
                for (int dn = 0; dn < 4; ++dn)
                    oacc[m][dn][r] *= cold;
            }

        #pragma unroll
        for (int m = 0; m < 4; ++m)
            #pragma unroll
            for (int n = 0; n < 4; ++n)
                #pragma unroll
                for (int r = 0; r < 4; ++r)
                    Pl[w][(m * 16 + grp * 4 + r) * 72 + n * 16 + c15] =
                        f2bf(s[m][n][r]);

        #pragma unroll
        for (int kc = 0; kc < 2; ++kc) {
            sx8 ap[4];
            #pragma unroll
            for (int m = 0; m < 4; ++m)
                ap[m] = *(const sx8*)&Pl[w][(m * 16 + c15) * 72 + kc * 32 + grp * 8];
            #pragma unroll
            for (int dn = 0; dn < 4; ++dn) {
                sx8 bv = *(const sx8*)&Vt[(dn * 16 + c15) * 264 + kt + kc * 32 + grp * 8];
                #pragma unroll
                for (int m = 0; m < 4; ++m)
                    oacc[m][dn] = __builtin_amdgcn_mfma_f32_16x16x32_bf16(
                        ap[m], bv, oacc[m][dn], 0, 0, 0);
            }
        }
    }

    #pragma unroll
    for (int m = 0; m < 4; ++m)
        #pragma unroll
        for (int r = 0; r < 4; ++r) {
            const float inv = 1.0f / l_s[m][r];
            const int row = bl * TSEQ + w * 64 + m * 16 + grp * 4 + r;
            ushort* yp = y + (size_t)row * C_DIM + h * HDIM;
            #pragma unroll
            for (int dn = 0; dn < 4; ++dn)
                yp[dn * 16 + c15] = f2bf(oacc[m][dn][r] * inv);
        }
}

// ---------------------------------------------------------------------------
extern "C" void kernel_launch(void* const* d_in, const int* in_sizes, int n_in,
                              void* d_out, int out_size, void* d_ws, size_t ws_size,
                              hipStream_t stream)
{
    const float* x      = (const float*)d_in[0];
    const float* ln1_w  = (const float*)d_in[1];
    const float* ln1_b  = (const float*)d_in[2];
    const float* w_attn = (const float*)d_in[3];
    const float* b_attn = (const float*)d_in[4];
    const float* w_proj = (const float*)d_in[5];
    const float* b_proj = (const float*)d_in[6];
    const float* ln2_w  = (const float*)d_in[7];
    const float* ln2_b  = (const float*)d_in[8];
    const float* w_fc   = (const float*)d_in[9];
    const float* b_fc   = (const float*)d_in[10];
    const float* w_out  = (const float*)d_in[11];
    const float* b_out  = (const float*)d_in[12];
    float* out = (float*)d_out;

    ushort* wbf     = (ushort*)d_ws;
    ushort* wt_attn = wbf;                 // 1024*3072
    ushort* wt_proj = wbf + 3145728;       // 1024*1024
    ushort* wt_fc   = wbf + 4194304;       // 1024*4096
    ushort* wt_out  = wbf + 8388608;       // 4096*1024
    const size_t wbytes = 12582912ull * 2;

    int nchunk = 64;
    for (int cand = 1; cand <= 64; cand *= 2) {
        const size_t rows = (size_t)(BATCH / cand) * TSEQ;
        if (wbytes + rows * 10240ull <= ws_size) { nchunk = cand; break; }
    }
    const int bchunk = BATCH / nchunk;
    const int rows   = bchunk * TSEQ;

    ushort* hbuf = wbf + 12582912;
    ushort* qkvb = hbuf + (size_t)rows * 1024;
    ushort* ybuf = qkvb + (size_t)rows * 3072;
    ushort* act  = qkvb;                   // rows*4096 spans qkvb+ybuf

    wconv<<<dim3(16, 48), 256, 0, stream>>>(w_attn, wt_attn, 1024, 3072);
    wconv<<<dim3(16, 16), 256, 0, stream>>>(w_proj, wt_proj, 1024, 1024);
    wconv<<<dim3(16, 64), 256, 0, stream>>>(w_fc,   wt_fc,   1024, 4096);
    wconv<<<dim3(64, 16), 256, 0, stream>>>(w_out,  wt_out,  4096, 1024);

    for (int c = 0; c < nchunk; ++c) {
        const size_t r0 = (size_t)c * rows;
        const float* xc = x   + r0 * C_DIM;
        float*       oc = out + r0 * C_DIM;
        ln_bf16<<<rows, 256, 0, stream>>>(xc, ln1_w, ln1_b, hbuf);
        gemm_mfma<0><<<dim3(rows / 128, 3072 / 128), 256, 0, stream>>>(
            hbuf, wt_attn, b_attn, nullptr, qkvb, rows, 3072, 1024);
        attn_mfma<<<bchunk * NHEAD, 256, 0, stream>>>(qkvb, ybuf);
        gemm_mfma<1><<<dim3(rows / 128, 1024 / 128), 256, 0, stream>>>(
            ybuf, wt_proj, b_proj, xc, oc, rows, 1024, 1024);
    }

    for (int c = 0; c < nchunk; ++c) {
        const size_t r0 = (size_t)c * rows;
        float* oc = out + r0 * C_DIM;
        ln_bf16<<<rows, 256, 0, stream>>>(oc, ln2_w, ln2_b, hbuf);
        gemm_mfma<2><<<dim3(rows / 128, 4096 / 128), 256, 0, stream>>>(
            hbuf, wt_fc, b_fc, nullptr, act, rows, 4096, 1024);
        gemm_mfma<1><<<dim3(rows / 128, 1024 / 128), 256, 0, stream>>>(
            act, wt_out, b_out, oc, oc, rows, 1024, 4096);
    }
}

// Round 15
// 924.936 us; speedup vs baseline: 1.1020x; 1.0552x over previous
//
#include <hip/hip_runtime.h>
#include <math.h>

// GPT-2 block forward. B=64, T=256, C=1024, H=16, D=64, M=16384.
// Round 15: (1) staging REVERTED to round-8 reg-staged form (measured best:
// fc 243us vs gload_lds 277/262 at this occupancy — measurement beats the
// m97 model here); (2) fc GELU epilogue switched from erff (~25-30 VALU ops,
// ~2500 cyc/wave = comparable to the whole K=1024 MFMA loop) to tanh-form
// GELU (~12 ops, max |delta| ~3e-4 << bf16 ULP). Attn/LN/wconv unchanged.

#define C_DIM   1024
#define NHEAD   16
#define HDIM    64
#define TSEQ    256
#define BATCH   64

typedef __attribute__((ext_vector_type(4))) float fx4;
typedef __attribute__((ext_vector_type(8))) short sx8;

__device__ __forceinline__ ushort f2bf(float f) {
    uint x = __float_as_uint(f);
    x += 0x7fffu + ((x >> 16) & 1u);          // round-to-nearest-even
    return (ushort)(x >> 16);
}
__device__ __forceinline__ float bf2f(ushort u) {
    return __uint_as_float(((uint)u) << 16);
}

// tanh-form GELU: 0.5x(1+tanh(0.79788456(x+0.044715x^3))).
// max |delta| vs exact-erf GELU ~3e-4, an order below bf16 rounding.
__device__ __forceinline__ float gelu_fast(float x) {
    const float z = 0.79788456080286536f * (x + 0.044715f * x * x * x);
    const float u = __expf(-2.0f * fabsf(z));
    float t = __fdividef(1.0f - u, 1.0f + u);   // tanh(|z|)
    t = copysignf(t, z);
    return 0.5f * x * (1.0f + t);
}

// ---------------------------------------------------------------------------
// Weight convert+transpose: W[K][N] fp32 -> Wt[N][K] bf16. 64x64 tiles.
// ---------------------------------------------------------------------------
__global__ __launch_bounds__(256)
void wconv(const float* __restrict__ W, ushort* __restrict__ Wt, int K, int N)
{
    __shared__ float T[64][65];
    const int kt = blockIdx.x << 6, nt = blockIdx.y << 6;
    const int ln = threadIdx.x & 63, g4 = threadIdx.x >> 6;
    #pragma unroll
    for (int i = 0; i < 16; ++i) {
        const int r = i * 4 + g4;
        T[r][ln] = W[(size_t)(kt + r) * N + nt + ln];
    }
    __syncthreads();
    #pragma unroll
    for (int i = 0; i < 16; ++i) {
        const int r = i * 4 + g4;
        Wt[(size_t)(nt + r) * K + kt + ln] = f2bf(T[ln][r]);
    }
}

// ---------------------------------------------------------------------------
// LayerNorm fp32 in -> bf16 out. One block per 1024-float row.
// ---------------------------------------------------------------------------
__global__ __launch_bounds__(256)
void ln_bf16(const float* __restrict__ x, const float* __restrict__ w,
             const float* __restrict__ b, ushort* __restrict__ out)
{
    const int row = blockIdx.x;
    const int tid = threadIdx.x;
    const float4 v = reinterpret_cast<const float4*>(x + (size_t)row * C_DIM)[tid];

    float s  = v.x + v.y + v.z + v.w;
    float ss = v.x * v.x + v.y * v.y + v.z * v.z + v.w * v.w;
    #pragma unroll
    for (int off = 32; off > 0; off >>= 1) {
        s  += __shfl_down(s, off);
        ss += __shfl_down(ss, off);
    }
    __shared__ float rs[4], rss[4];
    const int wid = tid >> 6, lane = tid & 63;
    if (lane == 0) { rs[wid] = s; rss[wid] = ss; }
    __syncthreads();
    if (tid == 0) {
        const float S  = rs[0] + rs[1] + rs[2] + rs[3];
        const float SS = rss[0] + rss[1] + rss[2] + rss[3];
        const float mu  = S * (1.0f / C_DIM);
        const float var = SS * (1.0f / C_DIM) - mu * mu;
        rs[0]  = mu;
        rss[0] = rsqrtf(var + 1e-5f);
    }
    __syncthreads();
    const float mu = rs[0], rstd = rss[0];

    const float4 wv = reinterpret_cast<const float4*>(w)[tid];
    const float4 bv = reinterpret_cast<const float4*>(b)[tid];
    ushort4 o;
    o.x = f2bf((v.x - mu) * rstd * wv.x + bv.x);
    o.y = f2bf((v.y - mu) * rstd * wv.y + bv.y);
    o.z = f2bf((v.z - mu) * rstd * wv.z + bv.z);
    o.w = f2bf((v.w - mu) * rstd * wv.w + bv.w);
    reinterpret_cast<ushort4*>(out + (size_t)row * C_DIM)[tid] = o;
}

// ---------------------------------------------------------------------------
// bf16 MFMA GEMM (NT): C[M,N] = A[M,K] * Wt[N,K]^T + bias (+res) (+gelu)
// 128x128 tile, BK=32, 256 threads (4 waves, 2x2), 64x64 per wave.
// Reg-staged double-stream (round-8 form, measured best): next tile's
// global loads into VGPRs issued before compute; LDS write next iter.
// EPI: 0 = bf16 out + bias; 1 = fp32 out + bias + res; 2 = bf16 out + bias + gelu
// ---------------------------------------------------------------------------
template<int EPI>
__global__ __launch_bounds__(256)
void gemm_mfma(const ushort* __restrict__ A, const ushort* __restrict__ Wt,
               const float* __restrict__ bias, const float* __restrict__ res,
               void* __restrict__ outv, int M, int N, int K)
{
    __shared__ ushort As[128 * 32];
    __shared__ ushort Bs[128 * 32];

    const int tid  = threadIdx.x;
    const int lane = tid & 63;
    const int wid  = tid >> 6;
    const int wr   = (wid >> 1) << 6;
    const int wc   = (wid & 1) << 6;
    const int bm = blockIdx.x << 7;
    const int bn = blockIdx.y << 7;

    const int srow = tid >> 2;
    const int spos = tid & 3;
    const int skg  = spos ^ ((srow >> 1) & 3);
    const size_t ga0 = (size_t)(bm + srow)      * K + skg * 8;
    const size_t ga1 = (size_t)(bm + srow + 64) * K + skg * 8;
    const size_t gb0 = (size_t)(bn + srow)      * K + skg * 8;
    const size_t gb1 = (size_t)(bn + srow + 64) * K + skg * 8;
    ushort* la0 = &As[srow * 32 + spos * 8];
    ushort* la1 = &As[(srow + 64) * 32 + spos * 8];
    ushort* lb0 = &Bs[srow * 32 + spos * 8];
    ushort* lb1 = &Bs[(srow + 64) * 32 + spos * 8];

    const int frow = lane & 15;
    const int fpos = ((lane >> 4) ^ ((frow >> 1) & 3)) * 8;
    int aoff[4], boff[4];
    #pragma unroll
    for (int i = 0; i < 4; ++i) {
        aoff[i] = (wr + i * 16 + frow) * 32 + fpos;
        boff[i] = (wc + i * 16 + frow) * 32 + fpos;
    }

    fx4 acc[4][4] = {};

    const int nk = K >> 5;
    sx8 ra0 = *(const sx8*)(A  + ga0);
    sx8 ra1 = *(const sx8*)(A  + ga1);
    sx8 rb0 = *(const sx8*)(Wt + gb0);
    sx8 rb1 = *(const sx8*)(Wt + gb1);

    for (int t = 0; t < nk; ++t) {
        __syncthreads();
        *(sx8*)la0 = ra0; *(sx8*)la1 = ra1;
        *(sx8*)lb0 = rb0; *(sx8*)lb1 = rb1;
        __syncthreads();
        if (t + 1 < nk) {
            const int ko = (t + 1) << 5;
            ra0 = *(const sx8*)(A  + ga0 + ko);
            ra1 = *(const sx8*)(A  + ga1 + ko);
            rb0 = *(const sx8*)(Wt + gb0 + ko);
            rb1 = *(const sx8*)(Wt + gb1 + ko);
        }
        sx8 af[4], bf[4];
        #pragma unroll
        for (int i = 0; i < 4; ++i) af[i] = *(const sx8*)&As[aoff[i]];
        #pragma unroll
        for (int i = 0; i < 4; ++i) bf[i] = *(const sx8*)&Bs[boff[i]];
        #pragma unroll
        for (int i = 0; i < 4; ++i)
            #pragma unroll
            for (int j = 0; j < 4; ++j)
                acc[i][j] = __builtin_amdgcn_mfma_f32_16x16x32_bf16(
                    af[i], bf[j], acc[i][j], 0, 0, 0);
    }

    // epilogue: D row = (lane>>4)*4 + reg, col = lane&15  [HW-verified m89/m91]
    const int r0 = bm + wr + (lane >> 4) * 4;
    const int c0 = bn + wc + (lane & 15);
    #pragma unroll
    for (int i = 0; i < 4; ++i) {
        #pragma unroll
        for (int r = 0; r < 4; ++r) {
            const int row = r0 + i * 16 + r;
            #pragma unroll
            for (int j = 0; j < 4; ++j) {
                const int col = c0 + j * 16;
                float v = acc[i][j][r] + bias[col];
                if (EPI == 1) {
                    v += res[(size_t)row * N + col];
                    ((float*)outv)[(size_t)row * N + col] = v;
                } else if (EPI == 2) {
                    v = gelu_fast(v);
                    ((ushort*)outv)[(size_t)row * N + col] = f2bf(v);
                } else {
                    ((ushort*)outv)[(size_t)row * N + col] = f2bf(v);
                }
            }
        }
    }
}

// ---------------------------------------------------------------------------
// MFMA flash attention (unchanged from round 8).
// ---------------------------------------------------------------------------
__global__ __launch_bounds__(256, 1)
void attn_mfma(const ushort* __restrict__ qkv, ushort* __restrict__ y)
{
    __shared__ ushort Ks[256 * 72];
    __shared__ ushort Vt[64 * 264];
    __shared__ ushort Pl[4][64 * 72];

    const int bl = blockIdx.x >> 4;
    const int h  = blockIdx.x & 15;
    const size_t base = (size_t)bl * TSEQ * 3072 + (size_t)h * HDIM;

    const int tid  = threadIdx.x;
    const int lane = tid & 63;
    const int w    = tid >> 6;
    const int c15  = lane & 15;
    const int grp  = lane >> 4;

    {
        const int kv = tid;
        const ushort* kp = qkv + base + (size_t)kv * 3072 + 1024;
        const ushort* vp = qkv + base + (size_t)kv * 3072 + 2048;
        #pragma unroll
        for (int j = 0; j < 8; ++j) {
            sx8 k8 = *(const sx8*)(kp + j * 8);
            *(sx8*)&Ks[kv * 72 + j * 8] = k8;
            sx8 v8 = *(const sx8*)(vp + j * 8);
            #pragma unroll
            for (int e = 0; e < 8; ++e)
                Vt[(j * 8 + e) * 264 + kv] = (ushort)v8[e];
        }
    }

    sx8 aq[4][2];
    #pragma unroll
    for (int m = 0; m < 4; ++m)
        #pragma unroll
        for (int kc = 0; kc < 2; ++kc) {
            const int qr = w * 64 + m * 16 + c15;
            aq[m][kc] = *(const sx8*)(qkv + base + (size_t)qr * 3072 + kc * 32 + grp * 8);
        }

    __syncthreads();

    fx4 oacc[4][4] = {};
    float m_s[4][4], l_s[4][4];
    #pragma unroll
    for (int m = 0; m < 4; ++m)
        #pragma unroll
        for (int r = 0; r < 4; ++r) { m_s[m][r] = -INFINITY; l_s[m][r] = 0.0f; }

    for (int t = 0; t <= w; ++t) {
        const int kt = t * 64;
        const bool diag = (t == w);

        fx4 s[4][4] = {};
        #pragma unroll
        for (int kc = 0; kc < 2; ++kc)
            #pragma unroll
            for (int n = 0; n < 4; ++n) {
                sx8 bk = *(const sx8*)&Ks[(kt + n * 16 + c15) * 72 + kc * 32 + grp * 8];
                #pragma unroll
                for (int m = 0; m < 4; ++m)
                    s[m][n] = __builtin_amdgcn_mfma_f32_16x16x32_bf16(
                        aq[m][kc], bk, s[m][n], 0, 0, 0);
            }

        #pragma unroll
        for (int m = 0; m < 4; ++m)
            #pragma unroll
            for (int n = 0; n < 4; ++n)
                #pragma unroll
                for (int r = 0; r < 4; ++r) {
                    float v = s[m][n][r] * 0.125f;
                    if (diag && (n * 16 + c15) > (m * 16 + grp * 4 + r)) v = -1e30f;
                    s[m][n][r] = v;
                }

        #pragma unroll
        for (int m = 0; m < 4; ++m)
            #pragma unroll
            for (int r = 0; r < 4; ++r) {
                float mx = fmaxf(fmaxf(s[m][0][r], s[m][1][r]),
                                 fmaxf(s[m][2][r], s[m][3][r]));
                #pragma unroll
                for (int off = 1; off < 16; off <<= 1)
                    mx = fmaxf(mx, __shfl_xor(mx, off));
                const float mnew = fmaxf(m_s[m][r], mx);
                const float cold = __expf(m_s[m][r] - mnew);
                m_s[m][r] = mnew;
                float rsum = 0.0f;
                #pragma unroll
                for (int n = 0; n < 4; ++n) {
                    const float p = __expf(s[m][n][r] - mnew);
                    s[m][n][r] = p;
                    rsum += p;
                }
                #pragma unroll
                for (int off = 1; off < 16; off <<= 1)
                    rsum += __shfl_xor(rsum, off);
                l_s[m][r] = l_s[m][r] * cold + rsum;
                #pragma unroll
                for (int dn = 0; dn < 4; ++dn)
                    oacc[m][dn][r] *= cold;
            }

        #pragma unroll
        for (int m = 0; m < 4; ++m)
            #pragma unroll
            for (int n = 0; n < 4; ++n)
                #pragma unroll
                for (int r = 0; r < 4; ++r)
                    Pl[w][(m * 16 + grp * 4 + r) * 72 + n * 16 + c15] =
                        f2bf(s[m][n][r]);

        #pragma unroll
        for (int kc = 0; kc < 2; ++kc) {
            sx8 ap[4];
            #pragma unroll
            for (int m = 0; m < 4; ++m)
                ap[m] = *(const sx8*)&Pl[w][(m * 16 + c15) * 72 + kc * 32 + grp * 8];
            #pragma unroll
            for (int dn = 0; dn < 4; ++dn) {
                sx8 bv = *(const sx8*)&Vt[(dn * 16 + c15) * 264 + kt + kc * 32 + grp * 8];
                #pragma unroll
                for (int m = 0; m < 4; ++m)
                    oacc[m][dn] = __builtin_amdgcn_mfma_f32_16x16x32_bf16(
                        ap[m], bv, oacc[m][dn], 0, 0, 0);
            }
        }
    }

    #pragma unroll
    for (int m = 0; m < 4; ++m)
        #pragma unroll
        for (int r = 0; r < 4; ++r) {
            const float inv = 1.0f / l_s[m][r];
            const int row = bl * TSEQ + w * 64 + m * 16 + grp * 4 + r;
            ushort* yp = y + (size_t)row * C_DIM + h * HDIM;
            #pragma unroll
            for (int dn = 0; dn < 4; ++dn)
                yp[dn * 16 + c15] = f2bf(oacc[m][dn][r] * inv);
        }
}

// ---------------------------------------------------------------------------
extern "C" void kernel_launch(void* const* d_in, const int* in_sizes, int n_in,
                              void* d_out, int out_size, void* d_ws, size_t ws_size,
                              hipStream_t stream)
{
    const float* x      = (const float*)d_in[0];
    const float* ln1_w  = (const float*)d_in[1];
    const float* ln1_b  = (const float*)d_in[2];
    const float* w_attn = (const float*)d_in[3];
    const float* b_attn = (const float*)d_in[4];
    const float* w_proj = (const float*)d_in[5];
    const float* b_proj = (const float*)d_in[6];
    const float* ln2_w  = (const float*)d_in[7];
    const float* ln2_b  = (const float*)d_in[8];
    const float* w_fc   = (const float*)d_in[9];
    const float* b_fc   = (const float*)d_in[10];
    const float* w_out  = (const float*)d_in[11];
    const float* b_out  = (const float*)d_in[12];
    float* out = (float*)d_out;

    ushort* wbf     = (ushort*)d_ws;
    ushort* wt_attn = wbf;                 // 1024*3072
    ushort* wt_proj = wbf + 3145728;       // 1024*1024
    ushort* wt_fc   = wbf + 4194304;       // 1024*4096
    ushort* wt_out  = wbf + 8388608;       // 4096*1024
    const size_t wbytes = 12582912ull * 2;

    int nchunk = 64;
    for (int cand = 1; cand <= 64; cand *= 2) {
        const size_t rows = (size_t)(BATCH / cand) * TSEQ;
        if (wbytes + rows * 10240ull <= ws_size) { nchunk = cand; break; }
    }
    const int bchunk = BATCH / nchunk;
    const int rows   = bchunk * TSEQ;

    ushort* hbuf = wbf + 12582912;
    ushort* qkvb = hbuf + (size_t)rows * 1024;
    ushort* ybuf = qkvb + (size_t)rows * 3072;
    ushort* act  = qkvb;                   // rows*4096 spans qkvb+ybuf

    wconv<<<dim3(16, 48), 256, 0, stream>>>(w_attn, wt_attn, 1024, 3072);
    wconv<<<dim3(16, 16), 256, 0, stream>>>(w_proj, wt_proj, 1024, 1024);
    wconv<<<dim3(16, 64), 256, 0, stream>>>(w_fc,   wt_fc,   1024, 4096);
    wconv<<<dim3(64, 16), 256, 0, stream>>>(w_out,  wt_out,  4096, 1024);

    for (int c = 0; c < nchunk; ++c) {
        const size_t r0 = (size_t)c * rows;
        const float* xc = x   + r0 * C_DIM;
        float*       oc = out + r0 * C_DIM;
        ln_bf16<<<rows, 256, 0, stream>>>(xc, ln1_w, ln1_b, hbuf);
        gemm_mfma<0><<<dim3(rows / 128, 3072 / 128), 256, 0, stream>>>(
            hbuf, wt_attn, b_attn, nullptr, qkvb, rows, 3072, 1024);
        attn_mfma<<<bchunk * NHEAD, 256, 0, stream>>>(qkvb, ybuf);
        gemm_mfma<1><<<dim3(rows / 128, 1024 / 128), 256, 0, stream>>>(
            ybuf, wt_proj, b_proj, xc, oc, rows, 1024, 1024);
    }

    for (int c = 0; c < nchunk; ++c) {
        const size_t r0 = (size_t)c * rows;
        float* oc = out + r0 * C_DIM;
        ln_bf16<<<rows, 256, 0, stream>>>(oc, ln2_w, ln2_b, hbuf);
        gemm_mfma<2><<<dim3(rows / 128, 4096 / 128), 256, 0, stream>>>(
            hbuf, wt_fc, b_fc, nullptr, act, rows, 4096, 1024);
        gemm_mfma<1><<<dim3(rows / 128, 1024 / 128), 256, 0, stream>>>(
            act, wt_out, b_out, oc, oc, rows, 1024, 4096);
    }
}